// Round 8
// baseline (116.041 us; speedup 1.0000x reference)
//
#include <hip/hip_runtime.h>
#include <cstdint>
#include <cstddef>

typedef unsigned short u16;
typedef __attribute__((ext_vector_type(8))) short short8;
typedef __attribute__((ext_vector_type(4))) float f32x4;

#define CIN   512
#define COUT  512
#define BATCH 16
#define HWSZ  1024      // 32*32
#define PADW  34        // 32 + 2 halo

static constexpr float MOD_SCALE  = 0.044194173824159216f;   // 1/sqrt(512)
static constexpr float CONV_SCALE = 0.014731391274719739f;   // 1/sqrt(512*9)

// workspace layout (bytes)
#define WS_S    0                              // 8192 f32   (32 KB)
#define WS_DSC  (32*1024)                      // 8192 f32   (32 KB)
#define WS_WSQ  (64*1024)                      // 262144 f32 (1 MB)
#define WS_WBT  (64*1024 + 1024*1024)          // 9*512*512 bf16 (4.5 MB)
#define WS_XSP  (WS_WBT + 9*512*512*2)         // 16*34*34*512 bf16 (~18 MB)

__device__ __forceinline__ u16 f2bf(float f) {
  union { float f; uint32_t u; } v; v.f = f;
  uint32_t r = v.u + 0x7fffu + ((v.u >> 16) & 1u);   // RNE
  return (u16)(r >> 16);
}

__device__ __forceinline__ void gload16(const void* g, void* l) {
  __builtin_amdgcn_global_load_lds(
      (const __attribute__((address_space(1))) void*)g,
      (__attribute__((address_space(3))) void*)l, 16, 0, 0);
}

// ---------------- s[b,i] = mod_scale * style[b,:] . mod_w[i,:] + mod_b[i] ----------------
__global__ void k_style(const float* __restrict__ style, const float* __restrict__ mod_w,
                        const float* __restrict__ mod_b, float* __restrict__ s_out) {
  int gid  = blockIdx.x * blockDim.x + threadIdx.x;
  int w    = gid >> 6, lane = gid & 63;
  int b    = w >> 9, i = w & 511;
  const float4* st = (const float4*)(style + (size_t)b * 512);
  const float4* mw = (const float4*)(mod_w + (size_t)i * 512);
  float4 a0 = st[lane * 2], a1 = st[lane * 2 + 1];
  float4 w0 = mw[lane * 2], w1 = mw[lane * 2 + 1];
  float acc = a0.x*w0.x + a0.y*w0.y + a0.z*w0.z + a0.w*w0.w
            + a1.x*w1.x + a1.y*w1.y + a1.z*w1.z + a1.w*w1.w;
  #pragma unroll
  for (int off = 32; off; off >>= 1) acc += __shfl_xor(acc, off);
  if (lane == 0) s_out[w] = acc * MOD_SCALE + mod_b[i];
}

// ---- fused: wsq[o,i] = sum_k w^2 ; wbt2[((kxy*64 + i/8)*512 + o)*8 + i%8] = bf16(w) ----
__global__ void k_wprep(const float* __restrict__ w, float* __restrict__ wsq,
                        u16* __restrict__ wbt2) {
  int idx = blockIdx.x * 256 + threadIdx.x;          // 262144 = o*512+i
  int o = idx >> 9, i = idx & 511;
  const float* p = w + (size_t)idx * 9;
  float a = 0.f;
  #pragma unroll
  for (int kxy = 0; kxy < 9; ++kxy) {
    float v = p[kxy];
    a += v * v;
    wbt2[((size_t)(kxy * 64 + (i >> 3)) * 512 + o) * 8 + (i & 7)] = f2bf(v);
  }
  wsq[idx] = a;
}

// ---------------- dscale[b,o] = conv_scale * rsqrt(cs^2 * sum_i wsq[o,i]*s[b,i]^2 + 1e-8) ----
__global__ void k_dscale(const float* __restrict__ wsq, const float* __restrict__ s,
                         float* __restrict__ dsc) {
  int gid  = blockIdx.x * blockDim.x + threadIdx.x;
  int w    = gid >> 6, lane = gid & 63;
  int b    = w >> 9, o = w & 511;
  const float4* q4 = (const float4*)(wsq + (size_t)o * 512);
  const float4* s4 = (const float4*)(s   + (size_t)b * 512);
  float4 q0 = q4[lane * 2], q1 = q4[lane * 2 + 1];
  float4 t0 = s4[lane * 2], t1 = s4[lane * 2 + 1];
  float acc = q0.x*t0.x*t0.x + q0.y*t0.y*t0.y + q0.z*t0.z*t0.z + q0.w*t0.w*t0.w
            + q1.x*t1.x*t1.x + q1.y*t1.y*t1.y + q1.z*t1.z*t1.z + q1.w*t1.w*t1.w;
  #pragma unroll
  for (int off = 32; off; off >>= 1) acc += __shfl_xor(acc, off);
  if (lane == 0)
    dsc[w] = CONV_SCALE * rsqrtf(acc * CONV_SCALE * CONV_SCALE + 1e-8f);
}

// ---------------- zero only the halo border of xs_p ----------------
__global__ void k_halo(u16* __restrict__ xsp) {
  int cell = blockIdx.x;      // 0..131 border cells of the 34x34 grid
  int b = blockIdx.y;
  int y, x;
  if (cell < 34)       { y = 0;          x = cell; }
  else if (cell < 68)  { y = 33;         x = cell - 34; }
  else if (cell < 100) { y = cell - 67;  x = 0; }    // 1..32
  else                 { y = cell - 99;  x = 33; }   // 1..32
  uint32_t* p = (uint32_t*)(xsp + ((size_t)(b * PADW + y) * PADW + x) * 512);
  p[threadIdx.x] = 0;   // 256 threads x 4B = 512 u16
}

// ---------------- xs_p[b][y+1][x+1][i] = bf16(x[b][i][y][x] * s[b][i])  (NCHW->NHWC) --------
__global__ void k_xs(const float* __restrict__ x, const float* __restrict__ s,
                     u16* __restrict__ xsp) {
  __shared__ float tile[64][33];
  int icb = blockIdx.x, y = blockIdx.y, b = blockIdx.z;
  int t = threadIdx.x;
  int i0 = icb * 64;
  int c  = t & 31;       // x coord
  int r0 = t >> 5;       // 0..7
  #pragma unroll
  for (int it = 0; it < 8; ++it) {
    int row = r0 + it * 8;                           // i_loc 0..63
    float sv = s[b * 512 + i0 + row];
    tile[row][c] = x[((size_t)(b * 512 + i0 + row)) * 1024 + y * 32 + c] * sv;
  }
  __syncthreads();
  int il = t & 63;
  int x0 = t >> 6;       // 0..3
  #pragma unroll
  for (int it = 0; it < 8; ++it) {
    int xc = x0 + it * 4;
    xsp[((size_t)((b * PADW + y + 1) * PADW) + (xc + 1)) * 512 + i0 + il] = f2bf(tile[il][xc]);
  }
}

// ---------------- implicit-GEMM conv + fused epilogue ----------------
// Tile 256(o) x 128(m), 4 waves each owning a 128x64 output tile, K=4608 in
// 144 steps of 32. NO BARRIERS: each wave owns a PRIVATE 36 KB LDS ring
// (A 3x8KB + B 3x4KB) staged via global_load_lds and drained by a per-wave
// counted vmcnt(12) (T4: stage(ks+2) always in flight, never drain to 0).
// Fragments for step ks+1 are ds_read into the spare register bank while the
// MFMA burst for step ks runs from the current bank -> no same-step LDS dep.
// A LDS layout [kc][128row][16B]: conflict-free reads, contiguous 1KB staging.
// B row-major [64row][64B] with bijective chunk XOR ((row&3)^((row>>2)&3)):
// 2-way residual (free). T1 XCD swizzle kept (grid 256 = 8x32).
__global__ __launch_bounds__(256, 1) void k_conv(
    const u16* __restrict__ wbt2, const u16* __restrict__ xsp,
    const float* __restrict__ dsc, const float* __restrict__ noise,
    const float* __restrict__ nw, const float* __restrict__ abias,
    float* __restrict__ out)
{
  extern __shared__ u16 SM[];   // 4 waves * 18432 u16 (36 KB) = 144 KB

  const int tid  = threadIdx.x;
  const int wave = tid >> 6, lane = tid & 63;

  // T1: XCD swizzle (grid 256 = 8 XCD x 32 contiguous tiles)
  const int bid = blockIdx.x;
  const int swz = (bid & 7) * 32 + (bid >> 3);
  const int o0 = (swz >> 7) << 8;     // 0 or 256
  const int m0 = (swz & 127) << 7;    // 0..16256
  const int b  = m0 >> 10;            // uniform per block

  const int wo = (wave >> 1) << 7;    // o sub-block: 0/128
  const int wm = (wave & 1) << 6;     // m sub-block: 0/64
  const int lrow = lane & 15;
  const int kc   = lane >> 4;         // 0..3 (16B k-chunk)

  u16* Abuf = &SM[wave * 18432];          // 3 slabs x 4096 u16
  u16* Bbuf = &SM[wave * 18432 + 12288];  // 3 slabs x 2048 u16

  // A global base (wbt2 layout [kxy*64+i8][o][8]): chunk index (4*ks + rc).
  const u16* gA = wbt2 + ((size_t)(o0 + wo) + lane) * 8;

  // B per-round global bases, source chunk pre-swizzled (rule #21)
  const u16* gB[4];
  #pragma unroll
  for (int r = 0; r < 4; ++r) {
    int row = r * 16 + (lane >> 2);
    int ck  = (lane & 3) ^ ((row & 3) ^ ((row >> 2) & 3));
    int mg  = m0 + wm + row;
    int yy = (mg >> 5) & 31, xx = mg & 31;
    gB[r] = xsp + ((size_t)(b * PADW + yy) * PADW + xx) * 512 + ck * 8;
  }

  f32x4 acc[8][4];
  #pragma unroll
  for (int i = 0; i < 8; ++i)
    #pragma unroll
    for (int j = 0; j < 4; ++j) acc[i][j] = (f32x4){0.f, 0.f, 0.f, 0.f};

  short8 av0[8], av1[8], bv0[4], bv1[4];   // double-banked fragments

  // stage step ks into slab s (A: 8 loads, B: 4 loads; 12 vmcnt entries)
  auto stage = [&](int ks, int s) {
    const u16* as = gA + (size_t)(4 * ks) * 4096;
    u16* ad = Abuf + s * 4096;
    #pragma unroll
    for (int r = 0; r < 8; ++r)
      gload16(as + (r >> 1) * 4096 + (r & 1) * 512,
              ad + (r >> 1) * 1024 + (r & 1) * 512);
    int kxy = ks >> 4;
    int ky = kxy / 3, kx = kxy - ky * 3;
    int offB = ((ky * PADW + kx) << 9) + (ks & 15) * 32;
    u16* bd = Bbuf + s * 2048;
    #pragma unroll
    for (int r = 0; r < 4; ++r)
      gload16(gB[r] + offB, bd + r * 512);
  };

#define RD(S, AV, BV)                                                     \
  {                                                                       \
    const u16* pa = Abuf + (S) * 4096 + kc * 1024 + lrow * 8;             \
    _Pragma("unroll")                                                     \
    for (int mi = 0; mi < 8; ++mi)                                        \
      AV[mi] = *(const short8*)(pa + mi * 128);                           \
    _Pragma("unroll")                                                     \
    for (int ni = 0; ni < 4; ++ni) {                                      \
      int row = ni * 16 + lrow;                                           \
      int ckr = kc ^ ((row & 3) ^ ((row >> 2) & 3));                      \
      BV[ni] = *(const short8*)(Bbuf + (S) * 2048 + row * 32 + ckr * 8);  \
    }                                                                     \
  }

#define COMPUTE(AV, BV)                                                   \
  _Pragma("unroll")                                                       \
  for (int mi = 0; mi < 8; ++mi)                                          \
    _Pragma("unroll")                                                     \
    for (int ni = 0; ni < 4; ++ni)                                        \
      acc[mi][ni] = __builtin_amdgcn_mfma_f32_16x16x32_bf16(              \
          AV[mi], BV[ni], acc[mi][ni], 0, 0, 0);

  // prologue: stage(0), stage(1); drain stage(0); pre-read bank0
  stage(0, 0);
  stage(1, 1);
  asm volatile("s_waitcnt vmcnt(12)" ::: "memory");
  RD(0, av0, bv0);

  // Step ks: stage(ks+2) -> slab (ks+2)%3 [private ring, within-wave ordering:
  // slab's last ds_reads were lgkm-drained before step ks-1's MFMAs];
  // vmcnt(12) [drains stage(ks+1), leaves stage(ks+2) in flight];
  // ds_read slab (ks+1)%3 -> bank (ks+1)&1; MFMA from bank ks&1 (registers).
#define STEP(KS, SNX, SRD, AVN, BVN, AVC, BVC, DOSTG, DORD, VM)          \
  {                                                                      \
    if (DOSTG) stage((KS) + 2, SNX);                                     \
    asm volatile("s_waitcnt vmcnt(" #VM ")" ::: "memory");               \
    if (DORD) RD(SRD, AVN, BVN);                                         \
    COMPUTE(AVC, BVC);                                                   \
  }

  for (int t = 0; t < 23; ++t) {
    const int k0 = t * 6;
    STEP(k0 + 0, 2, 1, av1, bv1, av0, bv0, 1, 1, 12);
    STEP(k0 + 1, 0, 2, av0, bv0, av1, bv1, 1, 1, 12);
    STEP(k0 + 2, 1, 0, av1, bv1, av0, bv0, 1, 1, 12);
    STEP(k0 + 3, 2, 1, av0, bv0, av1, bv1, 1, 1, 12);
    STEP(k0 + 4, 0, 2, av1, bv1, av0, bv0, 1, 1, 12);
    STEP(k0 + 5, 1, 0, av0, bv0, av1, bv1, 1, 1, 12);
  }
  // tail ks = 138..143
  STEP(138, 2, 1, av1, bv1, av0, bv0, 1, 1, 12);
  STEP(139, 0, 2, av0, bv0, av1, bv1, 1, 1, 12);
  STEP(140, 1, 0, av1, bv1, av0, bv0, 1, 1, 12);
  STEP(141, 2, 1, av0, bv0, av1, bv1, 1, 1, 12);  // stage(143) -> slab 2
  STEP(142, 0, 2, av1, bv1, av0, bv0, 0, 1, 0);   // drain stage(143); read it
  STEP(143, 0, 0, av0, bv0, av1, bv1, 0, 0, 0);
#undef STEP
#undef RD
#undef COMPUTE

  // epilogue: demod*conv_scale, noise, bias, leaky(0.2)*sqrt(2)
  const float nwv = nw[0];
  const int mrow = (lane >> 4) << 2;
  #pragma unroll
  for (int mi = 0; mi < 8; ++mi) {
    #pragma unroll
    for (int ni = 0; ni < 4; ++ni) {
      int mg = m0 + wm + ni * 16 + lrow;
      int hw = mg & 1023;
      float nz = nwv * noise[b * 1024 + hw];
      #pragma unroll
      for (int r = 0; r < 4; ++r) {
        int og = o0 + wo + mi * 16 + mrow + r;
        float v = acc[mi][ni][r] * dsc[b * 512 + og] + nz + abias[og];
        v = (v > 0.f ? v : 0.2f * v) * 1.4142135623730951f;
        out[(size_t)(b * 512 + og) * 1024 + hw] = v;
      }
    }
  }
}

extern "C" void kernel_launch(void* const* d_in, const int* in_sizes, int n_in,
                              void* d_out, int out_size, void* d_ws, size_t ws_size,
                              hipStream_t stream) {
  const float* x      = (const float*)d_in[0];
  const float* style  = (const float*)d_in[1];
  const float* noise  = (const float*)d_in[2];
  const float* weight = (const float*)d_in[3];
  const float* mod_w  = (const float*)d_in[4];
  const float* mod_b  = (const float*)d_in[5];
  const float* nw     = (const float*)d_in[6];
  const float* abias  = (const float*)d_in[7];
  float* out = (float*)d_out;

  char* ws = (char*)d_ws;
  float* s_buf = (float*)(ws + WS_S);
  float* dsc   = (float*)(ws + WS_DSC);
  float* wsq   = (float*)(ws + WS_WSQ);
  u16*   wbt2  = (u16*)(ws + WS_WBT);
  u16*   xsp   = (u16*)(ws + WS_XSP);

  // allow 144 KB dynamic LDS for k_conv (no-op if already set)
  hipFuncSetAttribute((const void*)k_conv,
                      hipFuncAttributeMaxDynamicSharedMemorySize, 147456);

  k_halo  <<<dim3(132, 16), 256, 0, stream>>>(xsp);
  k_style <<<2048, 256, 0, stream>>>(style, mod_w, mod_b, s_buf);
  k_wprep <<<1024, 256, 0, stream>>>(weight, wsq, wbt2);
  k_dscale<<<2048, 256, 0, stream>>>(wsq, s_buf, dsc);
  k_xs    <<<dim3(8, 32, 16), 256, 0, stream>>>(x, s_buf, xsp);
  k_conv  <<<256, 256, 147456, stream>>>(wbt2, xsp, dsc, noise, nw, abias, out);
}